// Round 10
// baseline (2372.419 us; speedup 1.0000x reference)
//
#include <hip/hip_runtime.h>
#include <math.h>

#define TS 512
#define NB 64
#define NF 64
#define NE 256
#define NH 512
#define NO 128

#define NGRP 4     // batch groups (16 rows each)
#define NSLC 64    // h-slices per group (8 h-idx each)
#define RPG  16    // rows per group (dense MFMA A)
#define SA   584   // LDS A row stride (bf16): 576 + 8 pad

// ws layout (float words)
#define OFF_WCOMB 0        // 2048*64
#define OFF_BCOMB 131072   // 2048
#define OFF_HBUF  133120   // u32[2][4][64][128] tagged h words = 65536
#define OFF_POOL  198656   // 64*512

typedef short bf16x8 __attribute__((ext_vector_type(8)));
typedef short bf16x4 __attribute__((ext_vector_type(4)));
typedef float f32x4 __attribute__((ext_vector_type(4)));
typedef unsigned long long u64;
typedef unsigned int u32;

union F8 { bf16x8 s; unsigned short u[8]; };
union F4 { bf16x4 s; unsigned short u[4]; };

__device__ __forceinline__ unsigned short f2bf(float f) {
    unsigned u = __float_as_uint(f);
    u += 0x7fffu + ((u >> 16) & 1u);
    return (unsigned short)(u >> 16);
}
__device__ __forceinline__ float bf2f(unsigned short h) {
    return __uint_as_float(((unsigned)h) << 16);
}
__device__ __forceinline__ float fast_sigmoid(float v) {
    return 1.f / (1.f + __expf(-v));
}
__device__ __forceinline__ float fast_tanh(float v) {
    return 1.f - 2.f / (1.f + __expf(2.f * v));
}
__device__ __forceinline__ u32 aload(const u32* p) {
    return __hip_atomic_load(p, __ATOMIC_RELAXED, __HIP_MEMORY_SCOPE_AGENT);
}

// W_comb[g][f] = sum_e W_ih[g][e] * W_emb[e][f];  b_comb[g] = W_ih[g]·b_emb + b_ih[g] + b_hh[g]
__global__ __launch_bounds__(256) void k_wcomb(const float* __restrict__ W_emb,
                                               const float* __restrict__ b_emb,
                                               const float* __restrict__ W_ih,
                                               const float* __restrict__ b_ih,
                                               const float* __restrict__ b_hh,
                                               float* __restrict__ W_comb,
                                               float* __restrict__ b_comb) {
    __shared__ float wih[4][NE];
    int g0 = blockIdx.x * 4;
    for (int i = threadIdx.x; i < 4 * NE; i += 256)
        wih[i >> 8][i & 255] = W_ih[(size_t)g0 * NE + i];
    __syncthreads();
    int gl = threadIdx.x >> 6, f = threadIdx.x & 63;
    float acc = 0.f;
    for (int e = 0; e < NE; ++e) acc += wih[gl][e] * W_emb[e * NF + f];
    W_comb[(size_t)(g0 + gl) * NF + f] = acc;
    if (f == 0) {
        float a2 = 0.f;
        for (int e = 0; e < NE; ++e) a2 += wih[gl][e] * b_emb[e];
        b_comb[g0 + gl] = a2 + b_ih[g0 + gl] + b_hh[g0 + gl];
    }
}

// Persistent LSTM, dense-A MFMA + wave-private dataflow staging.
// 256 WGs = 4 batch-groups x 64 gate-slices. Per WG/step [16x576]@[576x32].
// Waves own k-regions: w0..5 = 2 kt, w6 = kt12..14, w7 = kt15 + x(kt16,17).
// Each wave POLLS+STAGES exactly the A-region it MFMAs -> no barrier on the
// stage->MFMA edge (same-wave LDS program order). Only 2 barriers/step:
// #1 partials ready, #2 partials consumed. Poll: issue ALL unit loads first
// (parallel RTTs), then check/retry stale ones. Exchange word (R9-proven):
// {bf16hi<<16 | bf16lo&~3 | tag2}, tag2 = ((t+1)&3)^2; slab[parity][grp].
__global__ __launch_bounds__(512, 2) void k_lstm(const float* __restrict__ x,
                                                 const float* __restrict__ W_hh,
                                                 const float* __restrict__ W_comb,
                                                 const float* __restrict__ b_comb,
                                                 u32* __restrict__ hbuf,
                                                 float* __restrict__ pooled) {
    const int wg = blockIdx.x;
    const int grp = wg & 3;            // 0..3
    const int slc = wg >> 2;           // 0..63 -> h-idx [8*slc, 8*slc+8)
    const int tid = threadIdx.x;
    const int lane = tid & 63, wave = tid >> 6;
    const int m4 = lane & 15;          // A row (batch) / B col (gate)
    const int qq = lane >> 4;          // quad

    // k-region per wave: h-tiles [kt0, kt0+ktnh); MFMA tiles [kt0, kt0+mtn)
    const int kt0  = (wave < 6) ? wave * 2 : (wave == 6 ? 12 : 15);
    const int ktnh = (wave < 6) ? 2 : (wave == 6 ? 3 : 1);
    const int mtn  = (wave < 6) ? 2 : 3;           // wave7: kt15 + x16,17
    const int nIt  = 2 * ktnh;                     // poll units / 4 lanesets

    __shared__ __align__(16) unsigned short hAhi[RPG * SA];
    __shared__ __align__(16) unsigned short hAlo[RPG * SA];
    __shared__ __align__(16) float part[8 * 32 * 20];   // [wave][n_loc][b] pad 20
    __shared__ float bcl[32];

    // ---- B-fragments (split bf16, register-resident): 2 n-tiles x mtn ----
    F8 bhi[2][3], blo[2][3];
    #pragma unroll
    for (int nt = 0; nt < 2; ++nt) {
        const int n_loc = nt * 16 + m4;
        const int grow = (n_loc >> 3) * NH + slc * 8 + (n_loc & 7);
        #pragma unroll
        for (int k = 0; k < 3; ++k) {
            if (k < mtn) {
                const int kt = kt0 + k;
                const float* wp = (kt < 16)
                    ? W_hh   + (size_t)grow * NH + kt * 32 + qq * 8
                    : W_comb + (size_t)grow * NF + (kt - 16) * 32 + qq * 8;
                const float4 w0 = *(const float4*)wp;
                const float4 w1 = *(const float4*)(wp + 4);
                float wf[8] = {w0.x, w0.y, w0.z, w0.w, w1.x, w1.y, w1.z, w1.w};
                #pragma unroll
                for (int e = 0; e < 8; ++e) {
                    unsigned short hb = f2bf(wf[e]);
                    bhi[nt][k].u[e] = hb;
                    blo[nt][k].u[e] = f2bf(wf[e] - bf2f(hb));
                }
            }
        }
    }

    if (tid < 32) bcl[tid] = b_comb[(tid >> 3) * NH + slc * 8 + (tid & 7)];

    // zero h-section of A (t=0 state)
    for (int i = tid; i < 2048; i += 512) {
        const int r = i >> 7, c4 = (i & 127) << 2;
        *(u64*)&hAhi[r * SA + c4] = 0;
        *(u64*)&hAlo[r * SA + c4] = 0;
    }
    // wave 7: stage x(0), prefetch x(1). lane -> (r = lane>>2, c0 = (lane&3)*16)
    float4 xp[4];
    if (wave == 7) {
        const int r = lane >> 2, c0 = (lane & 3) * 16;
        #pragma unroll
        for (int i = 0; i < 4; ++i) {
            const float4 xv = *(const float4*)&x[((size_t)(grp * RPG + r) * TS + 0) * NF + c0 + 4 * i];
            float xf[4] = {xv.x, xv.y, xv.z, xv.w};
            F4 phi, plo;
            #pragma unroll
            for (int e = 0; e < 4; ++e) {
                unsigned short hb = f2bf(xf[e]);
                phi.u[e] = hb;
                plo.u[e] = f2bf(xf[e] - bf2f(hb));
            }
            *(bf16x4*)&hAhi[r * SA + NH + c0 + 4 * i] = phi.s;
            *(bf16x4*)&hAlo[r * SA + NH + c0 + 4 * i] = plo.s;
        }
        #pragma unroll
        for (int i = 0; i < 4; ++i)
            xp[i] = *(const float4*)&x[((size_t)(grp * RPG + r) * TS + 1) * NF + c0 + 4 * i];
    }

    float c_reg = 0.f, hsum = 0.f;  // live on tid<128
    __syncthreads();

    for (int t = 0; t < TS; ++t) {
        const bool last = (t + 1 == TS);

        // ---- MFMA: own k-region (A staged by THIS wave), 3 chains x 2 nt ----
        f32x4 acc[2][3];
        #pragma unroll
        for (int nt = 0; nt < 2; ++nt)
            #pragma unroll
            for (int c = 0; c < 3; ++c) acc[nt][c] = (f32x4){0.f, 0.f, 0.f, 0.f};
        #pragma unroll
        for (int k = 0; k < 3; ++k) {
            if (k < mtn) {
                const int kt = kt0 + k;
                const bf16x8 ah = *(const bf16x8*)&hAhi[m4 * SA + kt * 32 + qq * 8];
                const bf16x8 al = *(const bf16x8*)&hAlo[m4 * SA + kt * 32 + qq * 8];
                #pragma unroll
                for (int nt = 0; nt < 2; ++nt) {
                    acc[nt][0] = __builtin_amdgcn_mfma_f32_16x16x32_bf16(ah, bhi[nt][k].s, acc[nt][0], 0, 0, 0);
                    acc[nt][1] = __builtin_amdgcn_mfma_f32_16x16x32_bf16(al, bhi[nt][k].s, acc[nt][1], 0, 0, 0);
                    acc[nt][2] = __builtin_amdgcn_mfma_f32_16x16x32_bf16(ah, blo[nt][k].s, acc[nt][2], 0, 0, 0);
                }
            }
        }
        #pragma unroll
        for (int nt = 0; nt < 2; ++nt) {
            const f32x4 a = acc[nt][0] + acc[nt][1] + acc[nt][2];
            *(float4*)&part[wave * 640 + (nt * 16 + m4) * 20 + qq * 4] =
                make_float4(a.x, a.y, a.z, a.w);
        }
        __syncthreads();  // #1: partials ready

        // ---- epilogue part-read on tid<128: j = tid>>4 (0..7), b = tid&15 ----
        float v0 = 0.f, v1 = 0.f, v2 = 0.f, v3 = 0.f;
        if (tid < 128) {
            const int j = tid >> 4, b = tid & 15;
            #pragma unroll
            for (int ty = 0; ty < 4; ++ty) {
                const int n_loc = ty * 8 + j;
                float s = bcl[n_loc];
                #pragma unroll
                for (int w = 0; w < 8; ++w) s += part[w * 640 + n_loc * 20 + b];
                if (ty == 0) v0 = s; else if (ty == 1) v1 = s;
                else if (ty == 2) v2 = s; else v3 = s;
            }
        }
        __syncthreads();  // #2: partials consumed; part safe to rewrite next iter

        const unsigned tg2 = (unsigned)(((t + 1) & 3) ^ 2);
        u32* const slab = hbuf + ((size_t)((t & 1) * NGRP + grp)) * 8192;

        // ---- activations + c/h update + publish (waves 0,1) ----
        if (tid < 128) {
            const float iv = fast_sigmoid(v0);
            const float fv = fast_sigmoid(v1);
            const float gv = fast_tanh(v2);
            const float ov = fast_sigmoid(v3);
            c_reg = fv * c_reg + iv * gv;
            const float h = ov * fast_tanh(c_reg);
            hsum += h;
            if (!last) {
                const unsigned short hb = f2bf(h);
                const unsigned short lb = f2bf(h - bf2f(hb));
                const u32 pk = ((u32)hb << 16) | ((u32)lb & 0xFFFCu) | tg2;
                // slab[slc][j][b] -> offset slc*128 + tid ; 256B/wave full lines
                __hip_atomic_store(&slab[slc * 128 + tid], pk,
                                   __ATOMIC_RELAXED, __HIP_MEMORY_SCOPE_AGENT);
            }
        }

        // ---- wave-private poll + stage of OWN h-region for t+1 ----
        if (!last) {
            const int b = lane & 15, ui = lane >> 4;
            const int u0 = kt0 * 8;
            u32 r0[6], r1[6], r2[6], r3[6];
            // issue all units' loads (parallel RTTs)
            #pragma unroll
            for (int it = 0; it < 6; ++it) {
                if (it < nIt) {
                    const int uu = u0 + it * 4 + ui;
                    const u32* a0 = slab + (uu >> 1) * 128 + (uu & 1) * 64 + b;
                    r0[it] = aload(a0 + 0);
                    r1[it] = aload(a0 + 16);
                    r2[it] = aload(a0 + 32);
                    r3[it] = aload(a0 + 48);
                }
            }
            // check / retry / unpack / stage
            #pragma unroll
            for (int it = 0; it < 6; ++it) {
                if (it < nIt) {
                    const int uu = u0 + it * 4 + ui;
                    const u32* a0 = slab + (uu >> 1) * 128 + (uu & 1) * 64 + b;
                    u32 w0 = r0[it], w1 = r1[it], w2 = r2[it], w3 = r3[it];
                    int guard = 0;
                    while (((((w0 & 3) ^ tg2) | ((w1 & 3) ^ tg2)) |
                            (((w2 & 3) ^ tg2) | ((w3 & 3) ^ tg2))) != 0) {
                        __builtin_amdgcn_s_sleep(1);
                        w0 = aload(a0 + 0);
                        w1 = aload(a0 + 16);
                        w2 = aload(a0 + 32);
                        w3 = aload(a0 + 48);
                        if (++guard > (1 << 20)) break;  // anti-hang escape
                    }
                    const u64 hiP = (u64)(w0 >> 16) | ((u64)(w1 >> 16) << 16) |
                                    ((u64)(w2 >> 16) << 32) | ((u64)(w3 >> 16) << 48);
                    const u64 loP = (u64)(w0 & 0xFFFCu) | ((u64)(w1 & 0xFFFCu) << 16) |
                                    ((u64)(w2 & 0xFFFCu) << 32) | ((u64)(w3 & 0xFFFCu) << 48);
                    *(u64*)&hAhi[b * SA + (uu >> 1) * 8 + (uu & 1) * 4] = hiP;
                    *(u64*)&hAlo[b * SA + (uu >> 1) * 8 + (uu & 1) * 4] = loP;
                }
            }
            // wave 7: stage x(t+1) from prefetch, prefetch x(t+2)
            if (wave == 7) {
                const int r = lane >> 2, c0 = (lane & 3) * 16;
                #pragma unroll
                for (int i = 0; i < 4; ++i) {
                    float xf[4] = {xp[i].x, xp[i].y, xp[i].z, xp[i].w};
                    F4 phi, plo;
                    #pragma unroll
                    for (int e = 0; e < 4; ++e) {
                        unsigned short hb = f2bf(xf[e]);
                        phi.u[e] = hb;
                        plo.u[e] = f2bf(xf[e] - bf2f(hb));
                    }
                    *(bf16x4*)&hAhi[r * SA + NH + c0 + 4 * i] = phi.s;
                    *(bf16x4*)&hAlo[r * SA + NH + c0 + 4 * i] = plo.s;
                }
                if (t + 2 < TS) {
                    #pragma unroll
                    for (int i = 0; i < 4; ++i)
                        xp[i] = *(const float4*)&x[((size_t)(grp * RPG + r) * TS + (t + 2)) * NF + c0 + 4 * i];
                }
            }
        }
        // NO trailing barrier: each wave proceeds to its own MFMA (wave-private A)
    }

    if (tid < 128) {
        const int j = tid >> 4, b = tid & 15;
        pooled[(size_t)(grp * RPG + b) * NH + slc * 8 + j] = hsum * (1.f / TS);
    }
}

// out[b][o] = pooled[b]·W_fc[o] + b_fc[o]
__global__ __launch_bounds__(256) void k_fc(const float* __restrict__ pooled,
                                            const float* __restrict__ W_fc,
                                            const float* __restrict__ b_fc,
                                            float* __restrict__ out) {
    __shared__ float pl[2][NH];
    const int b0 = blockIdx.x * 2;
    for (int i = threadIdx.x; i < 2 * NH; i += 256)
        pl[i >> 9][i & 511] = pooled[(size_t)b0 * NH + i];
    __syncthreads();
    const int o = threadIdx.x & 127, bl = threadIdx.x >> 7;
    const float* wr = W_fc + (size_t)o * NH;
    float acc = 0.f;
    #pragma unroll 4
    for (int k = 0; k < NH; k += 4) {
        const float4 wv = *(const float4*)&wr[k];
        acc += pl[bl][k] * wv.x + pl[bl][k + 1] * wv.y +
               pl[bl][k + 2] * wv.z + pl[bl][k + 3] * wv.w;
    }
    out[(size_t)(b0 + bl) * NO + o] = acc + b_fc[o];
}

extern "C" void kernel_launch(void* const* d_in, const int* in_sizes, int n_in,
                              void* d_out, int out_size, void* d_ws, size_t ws_size,
                              hipStream_t stream) {
    const float* x     = (const float*)d_in[0];
    const float* W_emb = (const float*)d_in[1];
    const float* b_emb = (const float*)d_in[2];
    const float* W_ih  = (const float*)d_in[3];
    const float* W_hh  = (const float*)d_in[4];
    const float* b_ih  = (const float*)d_in[5];
    const float* b_hh  = (const float*)d_in[6];
    const float* W_fc  = (const float*)d_in[7];
    const float* b_fc  = (const float*)d_in[8];
    float* out = (float*)d_out;
    float* ws  = (float*)d_ws;

    float* W_comb = ws + OFF_WCOMB;
    float* b_comb = ws + OFF_BCOMB;
    u32*   hbuf   = (u32*)(ws + OFF_HBUF);
    float* pooled = ws + OFF_POOL;

    hipLaunchKernelGGL(k_wcomb, dim3(512), dim3(256), 0, stream,
                       W_emb, b_emb, W_ih, b_ih, b_hh, W_comb, b_comb);
    hipLaunchKernelGGL(k_lstm,  dim3(256), dim3(512), 0, stream,
                       x, W_hh, W_comb, b_comb, hbuf, pooled);
    hipLaunchKernelGGL(k_fc,    dim3(32),  dim3(256), 0, stream,
                       pooled, W_fc, b_fc, out);
}

// Round 11
// 1751.279 us; speedup vs baseline: 1.3547x; 1.3547x over previous
//
#include <hip/hip_runtime.h>
#include <math.h>

#define TS 512
#define NB 64
#define NF 64
#define NE 256
#define NH 512
#define NO 128

#define NGRP 4     // batch groups (16 rows each)
#define NSLC 64    // h-slices per group (8 h-idx each)
#define RPG  16    // rows per group (dense MFMA A)
#define SA   584   // LDS A row stride (bf16): 576 + 8 pad

// ws layout (float words)
#define OFF_WCOMB 0        // 2048*64
#define OFF_BCOMB 131072   // 2048
#define OFF_HBUF  133120   // u32[2][4][64][128] tagged h words = 65536
#define OFF_POOL  198656   // 64*512

typedef short bf16x8 __attribute__((ext_vector_type(8)));
typedef short bf16x4 __attribute__((ext_vector_type(4)));
typedef float f32x4 __attribute__((ext_vector_type(4)));
typedef unsigned long long u64;
typedef unsigned int u32;

union F8 { bf16x8 s; unsigned short u[8]; };
union F4 { bf16x4 s; unsigned short u[4]; };

__device__ __forceinline__ unsigned short f2bf(float f) {
    unsigned u = __float_as_uint(f);
    u += 0x7fffu + ((u >> 16) & 1u);
    return (unsigned short)(u >> 16);
}
__device__ __forceinline__ float bf2f(unsigned short h) {
    return __uint_as_float(((unsigned)h) << 16);
}
__device__ __forceinline__ float fast_sigmoid(float v) {
    return 1.f / (1.f + __expf(-v));
}
__device__ __forceinline__ float fast_tanh(float v) {
    return 1.f - 2.f / (1.f + __expf(2.f * v));
}
__device__ __forceinline__ u32 aload(const u32* p) {
    return __hip_atomic_load(p, __ATOMIC_RELAXED, __HIP_MEMORY_SCOPE_AGENT);
}

// W_comb[g][f] = sum_e W_ih[g][e] * W_emb[e][f];  b_comb[g] = W_ih[g]·b_emb + b_ih[g] + b_hh[g]
__global__ __launch_bounds__(256) void k_wcomb(const float* __restrict__ W_emb,
                                               const float* __restrict__ b_emb,
                                               const float* __restrict__ W_ih,
                                               const float* __restrict__ b_ih,
                                               const float* __restrict__ b_hh,
                                               float* __restrict__ W_comb,
                                               float* __restrict__ b_comb) {
    __shared__ float wih[4][NE];
    int g0 = blockIdx.x * 4;
    for (int i = threadIdx.x; i < 4 * NE; i += 256)
        wih[i >> 8][i & 255] = W_ih[(size_t)g0 * NE + i];
    __syncthreads();
    int gl = threadIdx.x >> 6, f = threadIdx.x & 63;
    float acc = 0.f;
    for (int e = 0; e < NE; ++e) acc += wih[gl][e] * W_emb[e * NF + f];
    W_comb[(size_t)(g0 + gl) * NF + f] = acc;
    if (f == 0) {
        float a2 = 0.f;
        for (int e = 0; e < NE; ++e) a2 += wih[gl][e] * b_emb[e];
        b_comb[g0 + gl] = a2 + b_ih[g0 + gl] + b_hh[g0 + gl];
    }
}

// Persistent LSTM, dense-A MFMA, ONE barrier per step.
// 256 WGs = 4 batch-groups x 64 gate-slices; per WG/step [16x576]@[576x32].
// Wave w owns k-tiles: w0..5 = {2w,2w+1}; w6 = {12,13,16(x)}; w7 = {14,15,17(x)}.
// Iteration: MFMA(own tiles) -> part[t&1] -> BARRIER -> epilogue+publish
// (waves 0,1) -> batched poll + stage own hA region (wave-private; no 2nd
// barrier) -> next MFMA. part[] double-buffered so the barrier covers both
// "partials ready" and "prev partials consumed". Exchange (R9-proven):
// u32 {bf16hi<<16 | bf16lo&~3 | tag2}, tag2 = ((t+1)&3)^2, slab[parity][grp],
// producer full-line stores, relaxed agent atomics only (no fences).
__global__ __launch_bounds__(512, 1) void k_lstm(const float* __restrict__ x,
                                                 const float* __restrict__ W_hh,
                                                 const float* __restrict__ W_comb,
                                                 const float* __restrict__ b_comb,
                                                 u32* __restrict__ hbuf,
                                                 float* __restrict__ pooled) {
    const int wg = blockIdx.x;
    const int grp = wg & 3;            // 0..3
    const int slc = wg >> 2;           // 0..63 -> h-idx [8*slc, 8*slc+8)
    const int tid = threadIdx.x;
    const int lane = tid & 63, wave = tid >> 6;
    const int m4 = lane & 15;          // A row (batch) / B col (gate)
    const int qq = lane >> 4;          // quad

    const int mtn = (wave < 6) ? 2 : 3;
    int kts[3];
    kts[0] = (wave < 6) ? 2 * wave : 12 + 2 * (wave - 6);
    kts[1] = kts[0] + 1;
    kts[2] = (wave < 6) ? 0 : 16 + (wave - 6);

    __shared__ __align__(16) unsigned short hAhi[RPG * SA];
    __shared__ __align__(16) unsigned short hAlo[RPG * SA];
    __shared__ __align__(16) float part[2 * 8 * 32 * 20];  // [p][wave][n_loc][b(pad20)]
    __shared__ float bcl[32];

    // ---- B-fragments (split bf16, register-resident): 2 n-tiles x mtn ----
    F8 bhi[2][3], blo[2][3];
    #pragma unroll
    for (int nt = 0; nt < 2; ++nt) {
        const int n_loc = nt * 16 + m4;
        const int grow = (n_loc >> 3) * NH + slc * 8 + (n_loc & 7);
        #pragma unroll
        for (int k = 0; k < 3; ++k) {
            if (k < mtn) {
                const int kt = kts[k];
                const float* wp = (kt < 16)
                    ? W_hh   + (size_t)grow * NH + kt * 32 + qq * 8
                    : W_comb + (size_t)grow * NF + (kt - 16) * 32 + qq * 8;
                const float4 w0 = *(const float4*)wp;
                const float4 w1 = *(const float4*)(wp + 4);
                float wf[8] = {w0.x, w0.y, w0.z, w0.w, w1.x, w1.y, w1.z, w1.w};
                #pragma unroll
                for (int e = 0; e < 8; ++e) {
                    unsigned short hb = f2bf(wf[e]);
                    bhi[nt][k].u[e] = hb;
                    blo[nt][k].u[e] = f2bf(wf[e] - bf2f(hb));
                }
            }
        }
    }

    if (tid < 32) bcl[tid] = b_comb[(tid >> 3) * NH + slc * 8 + (tid & 7)];

    // zero h-section of A (t=0 state)
    for (int i = tid; i < 2048; i += 512) {
        const int r = i >> 7, c4 = (i & 127) << 2;
        *(u64*)&hAhi[r * SA + c4] = 0;
        *(u64*)&hAlo[r * SA + c4] = 0;
    }
    // waves 6,7: stage x(0) into own x-tile, prefetch x(1)
    float4 xpa = make_float4(0.f, 0.f, 0.f, 0.f), xpb = xpa;
    if (wave >= 6) {
        const int r = lane >> 2;
        const int xoff = (wave - 6) * 32 + (lane & 3) * 8;   // col within x(64)
        const float* xr0 = x + ((size_t)(grp * RPG + r) * TS + 0) * NF + xoff;
        const float4 a = ((const float4*)xr0)[0];
        const float4 b4 = ((const float4*)xr0)[1];
        float xf[8] = {a.x, a.y, a.z, a.w, b4.x, b4.y, b4.z, b4.w};
        F8 phi, plo;
        #pragma unroll
        for (int e = 0; e < 8; ++e) {
            unsigned short hb = f2bf(xf[e]);
            phi.u[e] = hb;
            plo.u[e] = f2bf(xf[e] - bf2f(hb));
        }
        *(bf16x8*)&hAhi[r * SA + NH + xoff] = phi.s;
        *(bf16x8*)&hAlo[r * SA + NH + xoff] = plo.s;
        const float* xr1 = x + ((size_t)(grp * RPG + r) * TS + 1) * NF + xoff;
        xpa = ((const float4*)xr1)[0];
        xpb = ((const float4*)xr1)[1];
    }

    float c_reg = 0.f, hsum = 0.f;  // live on tid<128
    __syncthreads();

    for (int t = 0; t < TS; ++t) {
        const bool last = (t + 1 == TS);
        const int p = t & 1;

        // ---- MFMA: own k-tiles (A staged by THIS wave), 3 split chains x 2 nt ----
        f32x4 acc[2][3];
        #pragma unroll
        for (int nt = 0; nt < 2; ++nt)
            #pragma unroll
            for (int c = 0; c < 3; ++c) acc[nt][c] = (f32x4){0.f, 0.f, 0.f, 0.f};
        #pragma unroll
        for (int k = 0; k < 3; ++k) {
            if (k < mtn) {
                const int kt = kts[k];
                const bf16x8 ah = *(const bf16x8*)&hAhi[m4 * SA + kt * 32 + qq * 8];
                const bf16x8 al = *(const bf16x8*)&hAlo[m4 * SA + kt * 32 + qq * 8];
                #pragma unroll
                for (int nt = 0; nt < 2; ++nt) {
                    acc[nt][0] = __builtin_amdgcn_mfma_f32_16x16x32_bf16(ah, bhi[nt][k].s, acc[nt][0], 0, 0, 0);
                    acc[nt][1] = __builtin_amdgcn_mfma_f32_16x16x32_bf16(al, bhi[nt][k].s, acc[nt][1], 0, 0, 0);
                    acc[nt][2] = __builtin_amdgcn_mfma_f32_16x16x32_bf16(ah, blo[nt][k].s, acc[nt][2], 0, 0, 0);
                }
            }
        }
        #pragma unroll
        for (int nt = 0; nt < 2; ++nt) {
            const f32x4 a = acc[nt][0] + acc[nt][1] + acc[nt][2];
            *(float4*)&part[p * 5120 + wave * 640 + (nt * 16 + m4) * 20 + qq * 4] =
                make_float4(a.x, a.y, a.z, a.w);
        }
        __syncthreads();  // THE barrier: partials(p) ready; prev partials consumed

        const unsigned tg2 = (unsigned)(((t + 1) & 3) ^ 2);
        u32* const slab = hbuf + ((size_t)(p * NGRP + grp)) * 8192;

        // ---- fused epilogue + publish (waves 0,1): j = tid>>4, b = tid&15 ----
        if (tid < 128) {
            const int j = tid >> 4, b = tid & 15;
            float v[4];
            #pragma unroll
            for (int ty = 0; ty < 4; ++ty) {
                const int n_loc = ty * 8 + j;
                float s = bcl[n_loc];
                #pragma unroll
                for (int w = 0; w < 8; ++w) s += part[p * 5120 + w * 640 + n_loc * 20 + b];
                v[ty] = s;
            }
            const float iv = fast_sigmoid(v[0]);
            const float fv = fast_sigmoid(v[1]);
            const float gv = fast_tanh(v[2]);
            const float ov = fast_sigmoid(v[3]);
            c_reg = fv * c_reg + iv * gv;
            const float h = ov * fast_tanh(c_reg);
            hsum += h;
            if (!last) {
                const unsigned short hb = f2bf(h);
                const unsigned short lb = f2bf(h - bf2f(hb));
                const u32 pk = ((u32)hb << 16) | ((u32)lb & 0xFFFCu) | tg2;
                // slab[slc][j][b] word = slc*128 + tid -> 512B contiguous, full lines
                __hip_atomic_store(&slab[slc * 128 + tid], pk,
                                   __ATOMIC_RELAXED, __HIP_MEMORY_SCOPE_AGENT);
            }
        }

        // ---- wave-private poll (batched) + stage own hA region for t+1 ----
        if (!last) {
            const int b = lane & 15, ui = lane >> 4;
            const int sbase = kts[0] * 4;   // region slices [sbase, sbase+8)
            const u32* aptr[4];
            u32 w[4][4];
            #pragma unroll
            for (int it = 0; it < 4; ++it) {
                const int uu = it * 4 + ui;  // 0..15 -> (uslc = uu>>1, jj2 = uu&1)
                const u32* a0 = slab + (sbase + (uu >> 1)) * 128 + (uu & 1) * 64 + b;
                aptr[it] = a0;
                w[it][0] = aload(a0 + 0);
                w[it][1] = aload(a0 + 16);
                w[it][2] = aload(a0 + 32);
                w[it][3] = aload(a0 + 48);
            }
            int guard = 0;
            for (;;) {
                u32 bad = 0;
                #pragma unroll
                for (int it = 0; it < 4; ++it)
                    bad |= ((w[it][0] & 3) ^ tg2) | ((w[it][1] & 3) ^ tg2) |
                           ((w[it][2] & 3) ^ tg2) | ((w[it][3] & 3) ^ tg2);
                if (bad == 0) break;
                __builtin_amdgcn_s_sleep(1);
                #pragma unroll
                for (int it = 0; it < 4; ++it) {   // batch reload (parallel RTTs)
                    w[it][0] = aload(aptr[it] + 0);
                    w[it][1] = aload(aptr[it] + 16);
                    w[it][2] = aload(aptr[it] + 32);
                    w[it][3] = aload(aptr[it] + 48);
                }
                if (++guard > (1 << 20)) break;  // anti-hang escape
            }
            #pragma unroll
            for (int it = 0; it < 4; ++it) {
                const int uu = it * 4 + ui;
                const u64 hiP = (u64)(w[it][0] >> 16) | ((u64)(w[it][1] >> 16) << 16) |
                                ((u64)(w[it][2] >> 16) << 32) | ((u64)(w[it][3] >> 16) << 48);
                const u64 loP = (u64)(w[it][0] & 0xFFFCu) | ((u64)(w[it][1] & 0xFFFCu) << 16) |
                                ((u64)(w[it][2] & 0xFFFCu) << 32) | ((u64)(w[it][3] & 0xFFFCu) << 48);
                *(u64*)&hAhi[b * SA + (sbase + (uu >> 1)) * 8 + (uu & 1) * 4] = hiP;
                *(u64*)&hAlo[b * SA + (sbase + (uu >> 1)) * 8 + (uu & 1) * 4] = loP;
            }
            // waves 6,7: stage x(t+1) from prefetch regs, prefetch x(t+2)
            if (wave >= 6) {
                const int r = lane >> 2;
                const int xoff = (wave - 6) * 32 + (lane & 3) * 8;
                float xf[8] = {xpa.x, xpa.y, xpa.z, xpa.w, xpb.x, xpb.y, xpb.z, xpb.w};
                F8 phi, plo;
                #pragma unroll
                for (int e = 0; e < 8; ++e) {
                    unsigned short hb = f2bf(xf[e]);
                    phi.u[e] = hb;
                    plo.u[e] = f2bf(xf[e] - bf2f(hb));
                }
                *(bf16x8*)&hAhi[r * SA + NH + xoff] = phi.s;
                *(bf16x8*)&hAlo[r * SA + NH + xoff] = plo.s;
                if (t + 2 < TS) {
                    const float* xr = x + ((size_t)(grp * RPG + r) * TS + (t + 2)) * NF + xoff;
                    xpa = ((const float4*)xr)[0];
                    xpb = ((const float4*)xr)[1];
                }
            }
        }
        // no trailing barrier: each wave's next MFMA reads only its own region
    }

    if (tid < 128) {
        const int j = tid >> 4, b = tid & 15;
        pooled[(size_t)(grp * RPG + b) * NH + slc * 8 + j] = hsum * (1.f / TS);
    }
}

// out[b][o] = pooled[b]·W_fc[o] + b_fc[o]
__global__ __launch_bounds__(256) void k_fc(const float* __restrict__ pooled,
                                            const float* __restrict__ W_fc,
                                            const float* __restrict__ b_fc,
                                            float* __restrict__ out) {
    __shared__ float pl[2][NH];
    const int b0 = blockIdx.x * 2;
    for (int i = threadIdx.x; i < 2 * NH; i += 256)
        pl[i >> 9][i & 511] = pooled[(size_t)b0 * NH + i];
    __syncthreads();
    const int o = threadIdx.x & 127, bl = threadIdx.x >> 7;
    const float* wr = W_fc + (size_t)o * NH;
    float acc = 0.f;
    #pragma unroll 4
    for (int k = 0; k < NH; k += 4) {
        const float4 wv = *(const float4*)&wr[k];
        acc += pl[bl][k] * wv.x + pl[bl][k + 1] * wv.y +
               pl[bl][k + 2] * wv.z + pl[bl][k + 3] * wv.w;
    }
    out[(size_t)(b0 + bl) * NO + o] = acc + b_fc[o];
}

extern "C" void kernel_launch(void* const* d_in, const int* in_sizes, int n_in,
                              void* d_out, int out_size, void* d_ws, size_t ws_size,
                              hipStream_t stream) {
    const float* x     = (const float*)d_in[0];
    const float* W_emb = (const float*)d_in[1];
    const float* b_emb = (const float*)d_in[2];
    const float* W_ih  = (const float*)d_in[3];
    const float* W_hh  = (const float*)d_in[4];
    const float* b_ih  = (const float*)d_in[5];
    const float* b_hh  = (const float*)d_in[6];
    const float* W_fc  = (const float*)d_in[7];
    const float* b_fc  = (const float*)d_in[8];
    float* out = (float*)d_out;
    float* ws  = (float*)d_ws;

    float* W_comb = ws + OFF_WCOMB;
    float* b_comb = ws + OFF_BCOMB;
    u32*   hbuf   = (u32*)(ws + OFF_HBUF);
    float* pooled = ws + OFF_POOL;

    hipLaunchKernelGGL(k_wcomb, dim3(512), dim3(256), 0, stream,
                       W_emb, b_emb, W_ih, b_ih, b_hh, W_comb, b_comb);
    hipLaunchKernelGGL(k_lstm,  dim3(256), dim3(512), 0, stream,
                       x, W_hh, W_comb, b_comb, hbuf, pooled);
    hipLaunchKernelGGL(k_fc,    dim3(32),  dim3(256), 0, stream,
                       pooled, W_fc, b_fc, out);
}

// Round 12
// 1551.423 us; speedup vs baseline: 1.5292x; 1.1288x over previous
//
#include <hip/hip_runtime.h>
#include <math.h>

#define TS 512
#define NB 64
#define NF 64
#define NE 256
#define NH 512
#define NO 128

#define NGRP 4     // batch groups (16 rows each)
#define NSLC 64    // h-slices per group (8 h-idx each)
#define RPG  16    // rows per group (dense MFMA A)

// ws layout (float words)
#define OFF_WCOMB 0        // 2048*64
#define OFF_BCOMB 131072   // 2048
#define OFF_HBUF  133120   // u32[2][4][64][128] tagged h words = 65536
#define OFF_POOL  198656   // 64*512

typedef short bf16x8 __attribute__((ext_vector_type(8)));
typedef float f32x4 __attribute__((ext_vector_type(4)));
typedef unsigned long long u64;
typedef unsigned int u32;

union F8 { bf16x8 s; unsigned short u[8]; };

__device__ __forceinline__ unsigned short f2bf(float f) {
    unsigned u = __float_as_uint(f);
    u += 0x7fffu + ((u >> 16) & 1u);
    return (unsigned short)(u >> 16);
}
__device__ __forceinline__ float bf2f(unsigned short h) {
    return __uint_as_float(((unsigned)h) << 16);
}
__device__ __forceinline__ float fast_sigmoid(float v) {
    return 1.f / (1.f + __expf(-v));
}
__device__ __forceinline__ float fast_tanh(float v) {
    return 1.f - 2.f / (1.f + __expf(2.f * v));
}
__device__ __forceinline__ u32 aload(const u32* p) {
    return __hip_atomic_load(p, __ATOMIC_RELAXED, __HIP_MEMORY_SCOPE_AGENT);
}

// W_comb[g][f] = sum_e W_ih[g][e] * W_emb[e][f];  b_comb[g] = W_ih[g]·b_emb + b_ih[g] + b_hh[g]
__global__ __launch_bounds__(256) void k_wcomb(const float* __restrict__ W_emb,
                                               const float* __restrict__ b_emb,
                                               const float* __restrict__ W_ih,
                                               const float* __restrict__ b_ih,
                                               const float* __restrict__ b_hh,
                                               float* __restrict__ W_comb,
                                               float* __restrict__ b_comb) {
    __shared__ float wih[4][NE];
    int g0 = blockIdx.x * 4;
    for (int i = threadIdx.x; i < 4 * NE; i += 256)
        wih[i >> 8][i & 255] = W_ih[(size_t)g0 * NE + i];
    __syncthreads();
    int gl = threadIdx.x >> 6, f = threadIdx.x & 63;
    float acc = 0.f;
    for (int e = 0; e < NE; ++e) acc += wih[gl][e] * W_emb[e * NF + f];
    W_comb[(size_t)(g0 + gl) * NF + f] = acc;
    if (f == 0) {
        float a2 = 0.f;
        for (int e = 0; e < NE; ++e) a2 += wih[gl][e] * b_emb[e];
        b_comb[g0 + gl] = a2 + b_ih[g0 + gl] + b_hh[g0 + gl];
    }
}

// Persistent LSTM, dense-A MFMA, ONE barrier/step, REGISTER-DIRECT A-frags.
// 256 WGs = 4 batch-groups x 64 gate-slices; per WG/step [16x576]@[576x32].
// Wave w owns k-tiles: w0..5 = {2w,2w+1}; w6 = {12,13,16(x)}; w7 = {14,15,17(x)}.
// KEY (R12): lane (m4,qq) polls exactly the 16 slab words its MFMA A-fragment
// needs (slab[kt*4+qq][j][m4], j=0..7) and assembles bf16x8 frags IN REGISTERS
// — no LDS staging at all. LDS holds only part[] (dbuf) + bcl.
// Iteration: MFMA(own frags) -> part[t&1] -> BARRIER -> epilogue+publish
// (waves 0,1) -> per-wave poll(tag t+1, exp backoff) -> build frags -> next MFMA.
// Exchange u32 {bf16hi<<16 | bf16lo&~3 | tag2}, tag2 = ((t+1)&3)^2 (R9-proven).
__global__ __launch_bounds__(512, 1) void k_lstm(const float* __restrict__ x,
                                                 const float* __restrict__ W_hh,
                                                 const float* __restrict__ W_comb,
                                                 const float* __restrict__ b_comb,
                                                 u32* __restrict__ hbuf,
                                                 float* __restrict__ pooled) {
    const int wg = blockIdx.x;
    const int grp = wg & 3;            // 0..3
    const int slc = wg >> 2;           // 0..63 -> h-idx [8*slc, 8*slc+8)
    const int tid = threadIdx.x;
    const int lane = tid & 63, wave = tid >> 6;
    const int m4 = lane & 15;          // A row (batch) / B col (gate)
    const int qq = lane >> 4;          // quad

    const int mtn = (wave < 6) ? 2 : 3;
    int kts[3];
    kts[0] = (wave < 6) ? 2 * wave : 12 + 2 * (wave - 6);
    kts[1] = kts[0] + 1;
    kts[2] = (wave < 6) ? 0 : 16 + (wave - 6);

    __shared__ __align__(16) float part[2 * 8 * 32 * 20];  // [p][wave][n_loc][b(pad20)]
    __shared__ float bcl[32];

    // ---- B-fragments (split bf16, register-resident): 2 n-tiles x mtn ----
    F8 bhi[2][3], blo[2][3];
    #pragma unroll
    for (int nt = 0; nt < 2; ++nt) {
        const int n_loc = nt * 16 + m4;
        const int grow = (n_loc >> 3) * NH + slc * 8 + (n_loc & 7);
        #pragma unroll
        for (int k = 0; k < 3; ++k) {
            if (k < mtn) {
                const int kt = kts[k];
                const float* wp = (kt < 16)
                    ? W_hh   + (size_t)grow * NH + kt * 32 + qq * 8
                    : W_comb + (size_t)grow * NF + (kt - 16) * 32 + qq * 8;
                const float4 w0 = *(const float4*)wp;
                const float4 w1 = *(const float4*)(wp + 4);
                float wf[8] = {w0.x, w0.y, w0.z, w0.w, w1.x, w1.y, w1.z, w1.w};
                #pragma unroll
                for (int e = 0; e < 8; ++e) {
                    unsigned short hb = f2bf(wf[e]);
                    bhi[nt][k].u[e] = hb;
                    blo[nt][k].u[e] = f2bf(wf[e] - bf2f(hb));
                }
            }
        }
    }

    if (tid < 32) bcl[tid] = b_comb[(tid >> 3) * NH + slc * 8 + (tid & 7)];

    // ---- A-fragments in registers; t=0: h = 0 ----
    F8 ahi[3], alo[3];
    #pragma unroll
    for (int k = 0; k < 3; ++k) {
        ahi[k].s = (bf16x8){0, 0, 0, 0, 0, 0, 0, 0};
        alo[k].s = (bf16x8){0, 0, 0, 0, 0, 0, 0, 0};
    }
    float4 xpa = make_float4(0.f, 0.f, 0.f, 0.f), xpb = xpa;
    if (wave >= 6) {
        // x(0) direct -> frag; prefetch x(1). lane (m4,qq) owns row m4, cols
        // (wave-6)*32 + qq*8 .. +8 — exactly its A-fragment elements.
        const int xoff = (wave - 6) * 32 + qq * 8;
        const float* xr0 = x + ((size_t)(grp * RPG + m4) * TS + 0) * NF + xoff;
        const float4 a = ((const float4*)xr0)[0];
        const float4 b4 = ((const float4*)xr0)[1];
        float xf[8] = {a.x, a.y, a.z, a.w, b4.x, b4.y, b4.z, b4.w};
        #pragma unroll
        for (int e = 0; e < 8; ++e) {
            unsigned short hb = f2bf(xf[e]);
            ahi[2].u[e] = hb;
            alo[2].u[e] = f2bf(xf[e] - bf2f(hb));
        }
        const float* xr1 = x + ((size_t)(grp * RPG + m4) * TS + 1) * NF + xoff;
        xpa = ((const float4*)xr1)[0];
        xpb = ((const float4*)xr1)[1];
    }

    float c_reg = 0.f, hsum = 0.f;  // live on tid<128
    __syncthreads();  // bcl ready

    for (int t = 0; t < TS; ++t) {
        const bool last = (t + 1 == TS);
        const int p = t & 1;

        // ---- MFMA: own k-tiles, A-frags from registers, 3 split chains x 2 nt ----
        f32x4 acc[2][3];
        #pragma unroll
        for (int nt = 0; nt < 2; ++nt)
            #pragma unroll
            for (int c = 0; c < 3; ++c) acc[nt][c] = (f32x4){0.f, 0.f, 0.f, 0.f};
        #pragma unroll
        for (int k = 0; k < 3; ++k) {
            if (k < mtn) {
                const bf16x8 ah = ahi[k].s;
                const bf16x8 al = alo[k].s;
                #pragma unroll
                for (int nt = 0; nt < 2; ++nt) {
                    acc[nt][0] = __builtin_amdgcn_mfma_f32_16x16x32_bf16(ah, bhi[nt][k].s, acc[nt][0], 0, 0, 0);
                    acc[nt][1] = __builtin_amdgcn_mfma_f32_16x16x32_bf16(al, bhi[nt][k].s, acc[nt][1], 0, 0, 0);
                    acc[nt][2] = __builtin_amdgcn_mfma_f32_16x16x32_bf16(ah, blo[nt][k].s, acc[nt][2], 0, 0, 0);
                }
            }
        }
        #pragma unroll
        for (int nt = 0; nt < 2; ++nt) {
            const f32x4 a = acc[nt][0] + acc[nt][1] + acc[nt][2];
            *(float4*)&part[p * 5120 + wave * 640 + (nt * 16 + m4) * 20 + qq * 4] =
                make_float4(a.x, a.y, a.z, a.w);
        }
        __syncthreads();  // THE barrier: part(p) ready; part(p^1) consumed

        const unsigned tg2 = (unsigned)(((t + 1) & 3) ^ 2);
        u32* const slab = hbuf + ((size_t)(p * NGRP + grp)) * 8192;

        // ---- fused epilogue + publish (waves 0,1): j = tid>>4, b = tid&15 ----
        if (tid < 128) {
            const int j = tid >> 4, b = tid & 15;
            float v[4];
            #pragma unroll
            for (int ty = 0; ty < 4; ++ty) {
                const int n_loc = ty * 8 + j;
                float s = bcl[n_loc];
                #pragma unroll
                for (int w = 0; w < 8; ++w) s += part[p * 5120 + w * 640 + n_loc * 20 + b];
                v[ty] = s;
            }
            const float iv = fast_sigmoid(v[0]);
            const float fv = fast_sigmoid(v[1]);
            const float gv = fast_tanh(v[2]);
            const float ov = fast_sigmoid(v[3]);
            c_reg = fv * c_reg + iv * gv;
            const float h = ov * fast_tanh(c_reg);
            hsum += h;
            if (!last) {
                const unsigned short hb = f2bf(h);
                const unsigned short lb = f2bf(h - bf2f(hb));
                const u32 pk = ((u32)hb << 16) | ((u32)lb & 0xFFFCu) | tg2;
                // slab[slc][j][b] word = slc*128 + tid -> 512B contiguous, full lines
                __hip_atomic_store(&slab[slc * 128 + tid], pk,
                                   __ATOMIC_RELAXED, __HIP_MEMORY_SCOPE_AGENT);
            }
        }

        // ---- per-wave poll of own frag words + in-register assembly ----
        if (!last) {
            // lane (m4,qq) needs slab[kts[k]*4+qq][j=0..7][m4], k = 0,1
            const u32* b0 = slab + (kts[0] * 4 + qq) * 128 + m4;
            const u32* b1 = slab + (kts[1] * 4 + qq) * 128 + m4;
            u32 wd[16];
            #pragma unroll
            for (int j = 0; j < 8; ++j) wd[j] = aload(b0 + j * 16);
            #pragma unroll
            for (int j = 0; j < 8; ++j) wd[8 + j] = aload(b1 + j * 16);
            int guard = 0;
            for (;;) {
                u32 bad = 0;
                #pragma unroll
                for (int i = 0; i < 16; ++i) bad |= (wd[i] & 3) ^ tg2;
                if (bad == 0) break;
                // exponential backoff: avoid poll-storm positive feedback
                if (guard < 8)       __builtin_amdgcn_s_sleep(1);
                else if (guard < 64) __builtin_amdgcn_s_sleep(4);
                else                 __builtin_amdgcn_s_sleep(16);
                #pragma unroll
                for (int j = 0; j < 8; ++j) wd[j] = aload(b0 + j * 16);
                #pragma unroll
                for (int j = 0; j < 8; ++j) wd[8 + j] = aload(b1 + j * 16);
                if (++guard > (1 << 20)) break;  // anti-hang escape
            }
            #pragma unroll
            for (int j = 0; j < 8; ++j) {
                ahi[0].u[j] = (unsigned short)(wd[j] >> 16);
                alo[0].u[j] = (unsigned short)(wd[j] & 0xFFFCu);
                ahi[1].u[j] = (unsigned short)(wd[8 + j] >> 16);
                alo[1].u[j] = (unsigned short)(wd[8 + j] & 0xFFFCu);
            }
            // waves 6,7: x(t+1) frag from prefetch; prefetch x(t+2)
            if (wave >= 6) {
                const int xoff = (wave - 6) * 32 + qq * 8;
                float xf[8] = {xpa.x, xpa.y, xpa.z, xpa.w, xpb.x, xpb.y, xpb.z, xpb.w};
                #pragma unroll
                for (int e = 0; e < 8; ++e) {
                    unsigned short hb = f2bf(xf[e]);
                    ahi[2].u[e] = hb;
                    alo[2].u[e] = f2bf(xf[e] - bf2f(hb));
                }
                if (t + 2 < TS) {
                    const float* xr = x + ((size_t)(grp * RPG + m4) * TS + (t + 2)) * NF + xoff;
                    xpa = ((const float4*)xr)[0];
                    xpb = ((const float4*)xr)[1];
                }
            }
        }
        // no trailing barrier: A-frags are wave-private registers
    }

    if (tid < 128) {
        const int j = tid >> 4, b = tid & 15;
        pooled[(size_t)(grp * RPG + b) * NH + slc * 8 + j] = hsum * (1.f / TS);
    }
}

// out[b][o] = pooled[b]·W_fc[o] + b_fc[o]
__global__ __launch_bounds__(256) void k_fc(const float* __restrict__ pooled,
                                            const float* __restrict__ W_fc,
                                            const float* __restrict__ b_fc,
                                            float* __restrict__ out) {
    __shared__ float pl[2][NH];
    const int b0 = blockIdx.x * 2;
    for (int i = threadIdx.x; i < 2 * NH; i += 256)
        pl[i >> 9][i & 511] = pooled[(size_t)b0 * NH + i];
    __syncthreads();
    const int o = threadIdx.x & 127, bl = threadIdx.x >> 7;
    const float* wr = W_fc + (size_t)o * NH;
    float acc = 0.f;
    #pragma unroll 4
    for (int k = 0; k < NH; k += 4) {
        const float4 wv = *(const float4*)&wr[k];
        acc += pl[bl][k] * wv.x + pl[bl][k + 1] * wv.y +
               pl[bl][k + 2] * wv.z + pl[bl][k + 3] * wv.w;
    }
    out[(size_t)(b0 + bl) * NO + o] = acc + b_fc[o];
}

extern "C" void kernel_launch(void* const* d_in, const int* in_sizes, int n_in,
                              void* d_out, int out_size, void* d_ws, size_t ws_size,
                              hipStream_t stream) {
    const float* x     = (const float*)d_in[0];
    const float* W_emb = (const float*)d_in[1];
    const float* b_emb = (const float*)d_in[2];
    const float* W_ih  = (const float*)d_in[3];
    const float* W_hh  = (const float*)d_in[4];
    const float* b_ih  = (const float*)d_in[5];
    const float* b_hh  = (const float*)d_in[6];
    const float* W_fc  = (const float*)d_in[7];
    const float* b_fc  = (const float*)d_in[8];
    float* out = (float*)d_out;
    float* ws  = (float*)d_ws;

    float* W_comb = ws + OFF_WCOMB;
    float* b_comb = ws + OFF_BCOMB;
    u32*   hbuf   = (u32*)(ws + OFF_HBUF);
    float* pooled = ws + OFF_POOL;

    hipLaunchKernelGGL(k_wcomb, dim3(512), dim3(256), 0, stream,
                       W_emb, b_emb, W_ih, b_ih, b_hh, W_comb, b_comb);
    hipLaunchKernelGGL(k_lstm,  dim3(256), dim3(512), 0, stream,
                       x, W_hh, W_comb, b_comb, hbuf, pooled);
    hipLaunchKernelGGL(k_fc,    dim3(32),  dim3(256), 0, stream,
                       pooled, W_fc, b_fc, out);
}